// Round 9
// baseline (459.387 us; speedup 1.0000x reference)
//
#include <hip/hip_runtime.h>
#include <hip/hip_bf16.h>

// ---------------------------------------------------------------------------
// GraphActorNetwork: movement MLP (16->128->128->128) -> scatter-mean over
// edges -> phase MLP (128->128->128->1).
// Round 9 = round 8 with the compile fix (pk2 no longer uses
// __builtin_bit_cast on __hip_bfloat162; manual RNE pack instead).
// mov_mlp_mfma uses SWAPPED MFMA operands (compute D^T = mfma(W_frag,
// act_frag)): per-lane D fragment = 4 consecutive channels of one sample ->
// epilogue is 8x 8B contiguous LDS writes; bias folded into acc init;
// 128-row tiles. Round-7 profile: mov 177us, MfmaUtil 8%, VALUBusy 24%
// (epilogue-bound), bank-conflict 2e6. Rest unchanged (442us, absmax 2.9e-3).
// ---------------------------------------------------------------------------

typedef __attribute__((ext_vector_type(8))) short short8;
typedef __attribute__((ext_vector_type(4))) float f32x4;

union U8 { short8 s8; unsigned int u[4]; };

__device__ __forceinline__ float bf2f(unsigned short u) {
  return __uint_as_float(((unsigned int)u) << 16);
}
__device__ __forceinline__ unsigned short f2bf(float f) {
  unsigned int u = __float_as_uint(f);
  u = (u + 0x7fffu + ((u >> 16) & 1u)) >> 16;   // RNE
  return (unsigned short)u;
}
__device__ __forceinline__ unsigned int pk2(float a, float b) {
  return ((unsigned int)f2bf(b) << 16) | (unsigned int)f2bf(a);
}

// ---------------- weight prep: f32 -> bf16 transposed -----------------------
// w1t: [128 c][32 k] (k 16..31 zero);  w2t..w5t: [128 c][128 k]
__global__ __launch_bounds__(256)
void prep_weights(const float* __restrict__ W1, const float* __restrict__ W2,
                  const float* __restrict__ W3, const float* __restrict__ W4,
                  const float* __restrict__ W5,
                  unsigned short* __restrict__ w1t, unsigned short* __restrict__ w2t,
                  unsigned short* __restrict__ w3t, unsigned short* __restrict__ w4t,
                  unsigned short* __restrict__ w5t) {
  int t = blockIdx.x * blockDim.x + threadIdx.x;
  int stride = gridDim.x * blockDim.x;
  if (t < 128 * 32) {
    int c = t >> 5, k = t & 31;
    w1t[t] = (k < 16) ? f2bf(W1[k * 128 + c]) : 0;
  }
  for (int i = t; i < 128 * 128; i += stride) {
    int c = i >> 7, k = i & 127;
    w2t[i] = f2bf(W2[k * 128 + c]);
    w3t[i] = f2bf(W3[k * 128 + c]);
    w4t[i] = f2bf(W4[k * 128 + c]);
    w5t[i] = f2bf(W5[k * 128 + c]);
  }
}

// ---------------- movement MLP via MFMA, swapped operands -------------------
// Block: 256 threads = 4 waves, tile 128 rows x 128 cols.
// Wave w: rows (w&1)*64..+63 (4 rf frags), cols (w>>1)*64..+63 (4 cf frags).
// D^T = mfma(Wfrag, actfrag): lane holds sample = lane&15 (per rf), channels
// cf*16 + g*4 .. +3. sH bf16 [128 samples][128 ch], 16B granules (8 ch)
// XOR-swizzled: slot = granule ^ (sample&7).
__global__ __launch_bounds__(256)
void mov_mlp_mfma(const float* __restrict__ x,
                  const unsigned short* __restrict__ w1t,
                  const unsigned short* __restrict__ w2t,
                  const unsigned short* __restrict__ w3t,
                  const float* __restrict__ b1, const float* __restrict__ b2,
                  const float* __restrict__ b3,
                  unsigned short* __restrict__ hout, int nrows) {
  __shared__ unsigned short sH[128 * 128];   // 32 KB
  const int tid  = threadIdx.x;
  const int lane = tid & 63;
  const int w    = tid >> 6;
  const int li   = lane & 15;     // sample-in-frag (D col) / W row (A)
  const int g    = lane >> 4;     // k-group; D rows g*4..+3
  const int r0w  = (w & 1) * 64;  // wave row base
  const int c0   = (w >> 1) * 64; // wave col base
  const int rowBlk = blockIdx.x * 128;

  f32x4 acc[4][4];   // [rf][cf]
  short8 Bf[4][4];   // [ks][cf] weight A-frags

  // ---- layer 1: act from global x (K=32, k 16..31 zero) ----
#pragma unroll
  for (int cf = 0; cf < 4; ++cf) {
    float4 b4 = *(const float4*)&b1[c0 + cf * 16 + g * 4];
#pragma unroll
    for (int rf = 0; rf < 4; ++rf) {
      acc[rf][cf][0] = b4.x; acc[rf][cf][1] = b4.y;
      acc[rf][cf][2] = b4.z; acc[rf][cf][3] = b4.w;
    }
  }
  {
    short8 Ax[4];
#pragma unroll
    for (int rf = 0; rf < 4; ++rf) {
      U8 a; a.s8 = (short8)0;
      int row = rowBlk + r0w + rf * 16 + li;
      if (g < 2 && row < nrows) {
        const float* xp = x + (size_t)row * 16 + g * 8;
        float4 u0 = *(const float4*)xp;
        float4 u1 = *(const float4*)(xp + 4);
        a.u[0] = pk2(u0.x, u0.y); a.u[1] = pk2(u0.z, u0.w);
        a.u[2] = pk2(u1.x, u1.y); a.u[3] = pk2(u1.z, u1.w);
      }
      Ax[rf] = a.s8;
    }
    short8 B1[4];
#pragma unroll
    for (int cf = 0; cf < 4; ++cf)
      B1[cf] = *(const short8*)&w1t[(c0 + cf * 16 + li) * 32 + g * 8];
#pragma unroll
    for (int rf = 0; rf < 4; ++rf)
#pragma unroll
      for (int cf = 0; cf < 4; ++cf)
        acc[rf][cf] = __builtin_amdgcn_mfma_f32_16x16x32_bf16(B1[cf], Ax[rf], acc[rf][cf], 0, 0, 0);
  }

  // epilogue layer 1 -> sH (relu; bias already in acc)
#pragma unroll
  for (int rf = 0; rf < 4; ++rf) {
    int s = r0w + rf * 16 + li;
    unsigned short* dst = &sH[s * 128 + (g & 1) * 4];
    int sx = s & 7;
#pragma unroll
    for (int cf = 0; cf < 4; ++cf) {
      int gi = (c0 >> 3) + cf * 2 + (g >> 1);
      int slot = gi ^ sx;
      uint2 u;
      u.x = pk2(fmaxf(acc[rf][cf][0], 0.f), fmaxf(acc[rf][cf][1], 0.f));
      u.y = pk2(fmaxf(acc[rf][cf][2], 0.f), fmaxf(acc[rf][cf][3], 0.f));
      *(uint2*)(dst + slot * 8) = u;
    }
  }
  __syncthreads();

  // ---- layers 2 and 3 ----
  const unsigned short* wts[2] = { w2t, w3t };
  const float* bs[2] = { b2, b3 };
#pragma unroll 1
  for (int layer = 0; layer < 2; ++layer) {
    const unsigned short* wt = wts[layer];
    const float* bb = bs[layer];
#pragma unroll
    for (int ks = 0; ks < 4; ++ks)
#pragma unroll
      for (int cf = 0; cf < 4; ++cf)
        Bf[ks][cf] = *(const short8*)&wt[(c0 + cf * 16 + li) * 128 + ks * 32 + g * 8];

#pragma unroll
    for (int cf = 0; cf < 4; ++cf) {
      float4 b4 = *(const float4*)&bb[c0 + cf * 16 + g * 4];
#pragma unroll
      for (int rf = 0; rf < 4; ++rf) {
        acc[rf][cf][0] = b4.x; acc[rf][cf][1] = b4.y;
        acc[rf][cf][2] = b4.z; acc[rf][cf][3] = b4.w;
      }
    }

#pragma unroll
    for (int ks = 0; ks < 4; ++ks) {
      short8 Ar[4];
#pragma unroll
      for (int rf = 0; rf < 4; ++rf) {
        int s = r0w + rf * 16 + li;
        int slot = (ks * 4 + g) ^ (s & 7);
        Ar[rf] = *(const short8*)&sH[s * 128 + slot * 8];
      }
#pragma unroll
      for (int rf = 0; rf < 4; ++rf)
#pragma unroll
        for (int cf = 0; cf < 4; ++cf)
          acc[rf][cf] = __builtin_amdgcn_mfma_f32_16x16x32_bf16(Bf[ks][cf], Ar[rf], acc[rf][cf], 0, 0, 0);
    }
    __syncthreads();   // all sH reads done before overwrite

#pragma unroll
    for (int rf = 0; rf < 4; ++rf) {
      int s = r0w + rf * 16 + li;
      unsigned short* dst = &sH[s * 128 + (g & 1) * 4];
      int sx = s & 7;
#pragma unroll
      for (int cf = 0; cf < 4; ++cf) {
        int gi = (c0 >> 3) + cf * 2 + (g >> 1);
        int slot = gi ^ sx;
        uint2 u;
        u.x = pk2(fmaxf(acc[rf][cf][0], 0.f), fmaxf(acc[rf][cf][1], 0.f));
        u.y = pk2(fmaxf(acc[rf][cf][2], 0.f), fmaxf(acc[rf][cf][3], 0.f));
        *(uint2*)(dst + slot * 8) = u;
      }
    }
    __syncthreads();
  }

  // ---- coalesced copy-out: sH -> hout (16B/lane x 8) ----
  {
    int r  = tid >> 1;            // 0..127
    int hb = tid & 1;             // col half
    int grow = rowBlk + r;
    if (grow < nrows) {
#pragma unroll
      for (int i = 0; i < 8; ++i) {
        int gi = hb * 8 + i;
        int slot = gi ^ (r & 7);
        short8 v = *(const short8*)&sH[r * 128 + slot * 8];
        *(short8*)(hout + (size_t)grow * 128 + gi * 8) = v;
      }
    }
  }
}

// ---------------- CSR build ------------------------------------------------
__global__ __launch_bounds__(256)
void hist_kernel(const int* __restrict__ edst, int* __restrict__ cnt, int ne) {
  int i = blockIdx.x * blockDim.x + threadIdx.x;
  int stride = gridDim.x * blockDim.x;
  for (int e = i; e < ne; e += stride) atomicAdd(cnt + edst[e], 1);
}

// hierarchical scan: 1024 elems per block. s1: per-block sums.
__global__ __launch_bounds__(256)
void scan_sum_kernel(const int* __restrict__ cnt, int* __restrict__ bsum, int nph) {
  __shared__ int red[256];
  const int b = blockIdx.x, t = threadIdx.x;
  const int base = b * 1024 + t * 4;
  int s = 0;
#pragma unroll
  for (int i = 0; i < 4; ++i) {
    int idx = base + i;
    if (idx < nph) s += cnt[idx];
  }
  red[t] = s;
  __syncthreads();
  for (int d = 128; d > 0; d >>= 1) {
    if (t < d) red[t] += red[t + d];
    __syncthreads();
  }
  if (t == 0) bsum[b] = red[0];
}

// s2: exclusive scan of bsum[nb] (nb <= 256) -> boff; total -> *offs_end.
__global__ __launch_bounds__(256)
void scan_top_kernel(const int* __restrict__ bsum, int* __restrict__ boff,
                     int* __restrict__ offs_end, int nb) {
  __shared__ int part[256];
  const int t = threadIdx.x;
  part[t] = (t < nb) ? bsum[t] : 0;
  __syncthreads();
  for (int d = 1; d < 256; d <<= 1) {
    int v = (t >= d) ? part[t - d] : 0;
    __syncthreads();
    part[t] += v;
    __syncthreads();
  }
  if (t < nb) boff[t] = (t == 0) ? 0 : part[t - 1];
  if (t == 255) *offs_end = part[255];
}

// s3: per-block exclusive scan + base offset -> offs, cursor.
__global__ __launch_bounds__(256)
void scan_fill_kernel(const int* __restrict__ cnt, const int* __restrict__ boff,
                      int* __restrict__ offs, int* __restrict__ cursor, int nph) {
  __shared__ int part[256];
  const int b = blockIdx.x, t = threadIdx.x;
  const int base = b * 1024 + t * 4;
  int v[4];
  int s = 0;
#pragma unroll
  for (int i = 0; i < 4; ++i) {
    int idx = base + i;
    v[i] = (idx < nph) ? cnt[idx] : 0;
    s += v[i];
  }
  part[t] = s;
  __syncthreads();
  for (int d = 1; d < 256; d <<= 1) {
    int u = (t >= d) ? part[t - d] : 0;
    __syncthreads();
    part[t] += u;
    __syncthreads();
  }
  int run = boff[b] + ((t == 0) ? 0 : part[t - 1]);
#pragma unroll
  for (int i = 0; i < 4; ++i) {
    int idx = base + i;
    if (idx < nph) {
      offs[idx] = run;
      cursor[idx] = run;
      run += v[i];
    }
  }
}

__global__ __launch_bounds__(256)
void fill_kernel(const int* __restrict__ esrc, const int* __restrict__ edst,
                 int* __restrict__ cursor, int* __restrict__ csr, int ne) {
  int i = blockIdx.x * blockDim.x + threadIdx.x;
  int stride = gridDim.x * blockDim.x;
  for (int e = i; e < ne; e += stride) {
    int d = edst[e];
    int pos = atomicAdd(cursor + d, 1);
    csr[pos] = esrc[e];
  }
}

// ---------------- per-phase gather-reduce: one wave per phase ---------------
__global__ __launch_bounds__(256)
void agg_kernel(const unsigned short* __restrict__ h, const int* __restrict__ csr,
                const int* __restrict__ offs, unsigned short* __restrict__ agg,
                int nph) {
  const int w = (blockIdx.x * blockDim.x + threadIdx.x) >> 6;
  const int lane = threadIdx.x & 63;
  if (w >= nph) return;
  const int beg = offs[w], end = offs[w + 1];
  float a0 = 0.f, a1 = 0.f;
  for (int j = beg; j < end; ++j) {
    int s = csr[j];
    ushort2 v = *(const ushort2*)(h + (size_t)s * 128 + lane * 2);
    a0 += bf2f(v.x);
    a1 += bf2f(v.y);
  }
  const float sc = 1.f / (float)max(end - beg, 1);
  ushort2 o;
  o.x = f2bf(a0 * sc);
  o.y = f2bf(a1 * sc);
  *(ushort2*)(agg + (size_t)w * 128 + lane * 2) = o;
}

// ---------------- phase MLP via MFMA (unchanged from round 7) ---------------
__global__ __launch_bounds__(256)
void phase_mlp_mfma(const unsigned short* __restrict__ aggb,
                    const unsigned short* __restrict__ w4t,
                    const unsigned short* __restrict__ w5t,
                    const float* __restrict__ b4, const float* __restrict__ b5,
                    const float* __restrict__ W6, const float* __restrict__ b6,
                    float* __restrict__ logits, int nph) {
  __shared__ unsigned short sH[64 * 128];
  float* sPart = (float*)sH;   // reused (after barrier) for head partials
  const int tid  = threadIdx.x;
  const int lane = tid & 63;
  const int w    = tid >> 6;
  const int rloc = lane & 15;
  const int g    = lane >> 4;
  const int r0w  = (w & 1) * 32;
  const int c0   = (w >> 1) * 64;
  const int rowBlk = blockIdx.x * 64;

  f32x4 acc[2][4];
  short8 Bf[4][4];

  // ---- layer 4: A from aggb global ----
#pragma unroll
  for (int ks = 0; ks < 4; ++ks)
#pragma unroll
    for (int cf = 0; cf < 4; ++cf)
      Bf[ks][cf] = *(const short8*)&w4t[(c0 + cf * 16 + rloc) * 128 + ks * 32 + g * 8];
#pragma unroll
  for (int rf = 0; rf < 2; ++rf)
#pragma unroll
    for (int cf = 0; cf < 4; ++cf) acc[rf][cf] = (f32x4)0.f;

  {
    const int row0 = rowBlk + r0w + rloc;
    const int row1 = row0 + 16;
#pragma unroll
    for (int ks = 0; ks < 4; ++ks) {
      short8 A0 = (short8)0, A1 = (short8)0;
      if (row0 < nph) A0 = *(const short8*)&aggb[(size_t)row0 * 128 + ks * 32 + g * 8];
      if (row1 < nph) A1 = *(const short8*)&aggb[(size_t)row1 * 128 + ks * 32 + g * 8];
#pragma unroll
      for (int cf = 0; cf < 4; ++cf) {
        acc[0][cf] = __builtin_amdgcn_mfma_f32_16x16x32_bf16(A0, Bf[ks][cf], acc[0][cf], 0, 0, 0);
        acc[1][cf] = __builtin_amdgcn_mfma_f32_16x16x32_bf16(A1, Bf[ks][cf], acc[1][cf], 0, 0, 0);
      }
    }
  }

  // epilogue layer 4 -> sH (swizzled)
  {
    float bv[4];
#pragma unroll
    for (int cf = 0; cf < 4; ++cf) bv[cf] = b4[c0 + cf * 16 + rloc];
#pragma unroll
    for (int rf = 0; rf < 2; ++rf)
#pragma unroll
      for (int cf = 0; cf < 4; ++cf)
#pragma unroll
        for (int i = 0; i < 4; ++i) {
          int row = r0w + rf * 16 + g * 4 + i;
          int col = c0 + cf * 16 + rloc;
          float v = fmaxf(acc[rf][cf][i] + bv[cf], 0.f);
          sH[row * 128 + (((col >> 3) ^ (row & 7)) << 3) + (col & 7)] = f2bf(v);
        }
  }
  __syncthreads();

  // ---- layer 5: A from sH ----
#pragma unroll
  for (int ks = 0; ks < 4; ++ks)
#pragma unroll
    for (int cf = 0; cf < 4; ++cf)
      Bf[ks][cf] = *(const short8*)&w5t[(c0 + cf * 16 + rloc) * 128 + ks * 32 + g * 8];
#pragma unroll
  for (int rf = 0; rf < 2; ++rf)
#pragma unroll
    for (int cf = 0; cf < 4; ++cf) acc[rf][cf] = (f32x4)0.f;

#pragma unroll
  for (int ks = 0; ks < 4; ++ks) {
    short8 A0, A1;
    {
      int row = r0w + rloc;
      int slot = (ks * 4 + g) ^ (row & 7);
      A0 = *(const short8*)&sH[row * 128 + slot * 8];
    }
    {
      int row = r0w + 16 + rloc;
      int slot = (ks * 4 + g) ^ (row & 7);
      A1 = *(const short8*)&sH[row * 128 + slot * 8];
    }
#pragma unroll
    for (int cf = 0; cf < 4; ++cf) {
      acc[0][cf] = __builtin_amdgcn_mfma_f32_16x16x32_bf16(A0, Bf[ks][cf], acc[0][cf], 0, 0, 0);
      acc[1][cf] = __builtin_amdgcn_mfma_f32_16x16x32_bf16(A1, Bf[ks][cf], acc[1][cf], 0, 0, 0);
    }
  }

  // ---- head: logits[r] = relu(acc + b5) . W6 + b6 ----
  float part8[2][4];
  {
    float bv[4], wv[4];
#pragma unroll
    for (int cf = 0; cf < 4; ++cf) {
      bv[cf] = b5[c0 + cf * 16 + rloc];
      wv[cf] = W6[c0 + cf * 16 + rloc];
    }
#pragma unroll
    for (int rf = 0; rf < 2; ++rf)
#pragma unroll
      for (int i = 0; i < 4; ++i) {
        float p = 0.f;
#pragma unroll
        for (int cf = 0; cf < 4; ++cf)
          p += fmaxf(acc[rf][cf][i] + bv[cf], 0.f) * wv[cf];
        part8[rf][i] = p;
      }
  }
#pragma unroll
  for (int m = 1; m < 16; m <<= 1) {
#pragma unroll
    for (int rf = 0; rf < 2; ++rf)
#pragma unroll
      for (int i = 0; i < 4; ++i)
        part8[rf][i] += __shfl_xor(part8[rf][i], m, 64);
  }
  __syncthreads();
  if (rloc == 0) {
#pragma unroll
    for (int rf = 0; rf < 2; ++rf)
#pragma unroll
      for (int i = 0; i < 4; ++i)
        sPart[(w >> 1) * 64 + r0w + rf * 16 + g * 4 + i] = part8[rf][i];
  }
  __syncthreads();
  if (tid < 64) {
    int gr = rowBlk + tid;
    if (gr < nph) logits[gr] = sPart[tid] + sPart[64 + tid] + b6[0];
  }
}

// ---------------------------------------------------------------------------
extern "C" void kernel_launch(void* const* d_in, const int* in_sizes, int n_in,
                              void* d_out, int out_size, void* d_ws, size_t ws_size,
                              hipStream_t stream) {
  const float* x  = (const float*)d_in[0];
  const float* W1 = (const float*)d_in[1];
  const float* b1 = (const float*)d_in[2];
  const float* W2 = (const float*)d_in[3];
  const float* b2 = (const float*)d_in[4];
  const float* W3 = (const float*)d_in[5];
  const float* b3 = (const float*)d_in[6];
  const float* W4 = (const float*)d_in[7];
  const float* b4 = (const float*)d_in[8];
  const float* W5 = (const float*)d_in[9];
  const float* b5 = (const float*)d_in[10];
  const float* W6 = (const float*)d_in[11];
  const float* b6 = (const float*)d_in[12];
  const int* esrc = (const int*)d_in[13];
  const int* edst = (const int*)d_in[14];

  const int nmov = in_sizes[0] / 16;
  const int ne   = in_sizes[13];
  const int nph  = out_size;

  char* ws = (char*)d_ws;
  size_t off = 0;
  auto take = [&](size_t bytes) {
    char* p = ws + off;
    off = (off + bytes + 255) & ~(size_t)255;
    return p;
  };
  unsigned short* hbuf = (unsigned short*)take((size_t)nmov * 128 * 2); // 128 MB
  int* csr             = (int*)take((size_t)ne * 4);                   //   4 MB
  int* cnt             = (int*)take((size_t)nph * 4);
  int* offs            = (int*)take(((size_t)nph + 1) * 4);
  int* cursor          = (int*)take((size_t)nph * 4);
  unsigned short* aggb = (unsigned short*)take((size_t)nph * 128 * 2); //  32 MB
  unsigned short* w1t  = (unsigned short*)take(128 * 32 * 2);
  unsigned short* w2t  = (unsigned short*)take(128 * 128 * 2);
  unsigned short* w3t  = (unsigned short*)take(128 * 128 * 2);
  unsigned short* w4t  = (unsigned short*)take(128 * 128 * 2);
  unsigned short* w5t  = (unsigned short*)take(128 * 128 * 2);
  const int nb = (nph + 1023) / 1024;            // <= 256 for nph <= 262144
  int* bsum            = (int*)take((size_t)nb * 4);
  int* boff            = (int*)take((size_t)nb * 4);
  if (off > ws_size) return;

  (void)hipMemsetAsync(cnt, 0, (size_t)nph * 4, stream);

  prep_weights<<<64, 256, 0, stream>>>(W1, W2, W3, W4, W5, w1t, w2t, w3t, w4t, w5t);

  int movBlocks = (nmov + 127) / 128;
  mov_mlp_mfma<<<movBlocks, 256, 0, stream>>>(x, w1t, w2t, w3t, b1, b2, b3, hbuf, nmov);

  hist_kernel<<<1024, 256, 0, stream>>>(edst, cnt, ne);
  scan_sum_kernel<<<nb, 256, 0, stream>>>(cnt, bsum, nph);
  scan_top_kernel<<<1, 256, 0, stream>>>(bsum, boff, offs + nph, nb);
  scan_fill_kernel<<<nb, 256, 0, stream>>>(cnt, boff, offs, cursor, nph);
  fill_kernel<<<1024, 256, 0, stream>>>(esrc, edst, cursor, csr, ne);

  int aggBlocks = (nph + 3) / 4;
  agg_kernel<<<aggBlocks, 256, 0, stream>>>(hbuf, csr, offs, aggb, nph);

  int phBlocks = (nph + 63) / 64;
  phase_mlp_mfma<<<phBlocks, 256, 0, stream>>>(aggb, w4t, w5t, b4, b5, W6, b6,
                                               (float*)d_out, nph);
}

// Round 10
// 379.685 us; speedup vs baseline: 1.2099x; 1.2099x over previous
//
#include <hip/hip_runtime.h>
#include <hip/hip_bf16.h>

// ---------------------------------------------------------------------------
// GraphActorNetwork: movement MLP (16->128->128->128) -> scatter-mean over
// edges -> phase MLP (128->128->128->1).
// Round 10: (1) mov_mlp_mfma hybrid = round-7 geometry (64-row tile, 2 rf,
// VGPR<128 -> occupancy back) + round-9 vectorized swapped-operand epilogue
// (D^T frag -> 8B contiguous LDS writes, bias folded). Round-9's 128-row
// tile crossed the 128-VGPR occupancy cliff (occ 32%->11%) and regressed.
// (2) agg_kernel rewritten with 4-edge ILP: 32-lane phase groups, 4
// independent gathers in flight (was 1 wave/phase, 1 serial gather/step,
// ~100us latency-bound). Rest unchanged (459us, absmax 2.9e-3).
// ---------------------------------------------------------------------------

typedef __attribute__((ext_vector_type(8))) short short8;
typedef __attribute__((ext_vector_type(4))) float f32x4;

union U8 { short8 s8; unsigned int u[4]; };

__device__ __forceinline__ float bf2f(unsigned short u) {
  return __uint_as_float(((unsigned int)u) << 16);
}
__device__ __forceinline__ unsigned short f2bf(float f) {
  unsigned int u = __float_as_uint(f);
  u = (u + 0x7fffu + ((u >> 16) & 1u)) >> 16;   // RNE
  return (unsigned short)u;
}
__device__ __forceinline__ unsigned int pk2(float a, float b) {
  return ((unsigned int)f2bf(b) << 16) | (unsigned int)f2bf(a);
}

// ---------------- weight prep: f32 -> bf16 transposed -----------------------
// w1t: [128 c][32 k] (k 16..31 zero);  w2t..w5t: [128 c][128 k]
__global__ __launch_bounds__(256)
void prep_weights(const float* __restrict__ W1, const float* __restrict__ W2,
                  const float* __restrict__ W3, const float* __restrict__ W4,
                  const float* __restrict__ W5,
                  unsigned short* __restrict__ w1t, unsigned short* __restrict__ w2t,
                  unsigned short* __restrict__ w3t, unsigned short* __restrict__ w4t,
                  unsigned short* __restrict__ w5t) {
  int t = blockIdx.x * blockDim.x + threadIdx.x;
  int stride = gridDim.x * blockDim.x;
  if (t < 128 * 32) {
    int c = t >> 5, k = t & 31;
    w1t[t] = (k < 16) ? f2bf(W1[k * 128 + c]) : 0;
  }
  for (int i = t; i < 128 * 128; i += stride) {
    int c = i >> 7, k = i & 127;
    w2t[i] = f2bf(W2[k * 128 + c]);
    w3t[i] = f2bf(W3[k * 128 + c]);
    w4t[i] = f2bf(W4[k * 128 + c]);
    w5t[i] = f2bf(W5[k * 128 + c]);
  }
}

// ---------------- movement MLP via MFMA, swapped operands, 64-row tile ------
// Block: 256 threads = 4 waves, tile 64 rows x 128 cols.
// Wave w: rows (w&1)*32..+31 (2 rf), cols (w>>1)*64..+63 (4 cf).
// D^T = mfma(Wfrag, actfrag): lane holds sample li (per rf), channels
// cf*16 + g*4..+3. sH bf16 [64 samples][128 ch], 16B granules (8 ch)
// XOR-swizzled: slot = granule ^ (sample&7).
__global__ __launch_bounds__(256)
void mov_mlp_mfma(const float* __restrict__ x,
                  const unsigned short* __restrict__ w1t,
                  const unsigned short* __restrict__ w2t,
                  const unsigned short* __restrict__ w3t,
                  const float* __restrict__ b1, const float* __restrict__ b2,
                  const float* __restrict__ b3,
                  unsigned short* __restrict__ hout, int nrows) {
  __shared__ unsigned short sH[64 * 128];   // 16 KB
  const int tid  = threadIdx.x;
  const int lane = tid & 63;
  const int w    = tid >> 6;
  const int li   = lane & 15;     // sample-in-frag
  const int g    = lane >> 4;     // k-group; D^T ch sub-block g*4..+3
  const int r0w  = (w & 1) * 32;  // wave row base
  const int c0   = (w >> 1) * 64; // wave col base
  const int rowBlk = blockIdx.x * 64;

  f32x4 acc[2][4];   // [rf][cf]
  short8 Bf[4][4];   // [ks][cf] hoisted weight frags

  // ---- layer 1: act from global x (K=32, k 16..31 zero) ----
#pragma unroll
  for (int cf = 0; cf < 4; ++cf) {
    float4 b4 = *(const float4*)&b1[c0 + cf * 16 + g * 4];
#pragma unroll
    for (int rf = 0; rf < 2; ++rf) {
      acc[rf][cf][0] = b4.x; acc[rf][cf][1] = b4.y;
      acc[rf][cf][2] = b4.z; acc[rf][cf][3] = b4.w;
    }
  }
  {
    short8 Ax[2];
#pragma unroll
    for (int rf = 0; rf < 2; ++rf) {
      U8 a; a.s8 = (short8)0;
      int row = rowBlk + r0w + rf * 16 + li;
      if (g < 2 && row < nrows) {
        const float* xp = x + (size_t)row * 16 + g * 8;
        float4 u0 = *(const float4*)xp;
        float4 u1 = *(const float4*)(xp + 4);
        a.u[0] = pk2(u0.x, u0.y); a.u[1] = pk2(u0.z, u0.w);
        a.u[2] = pk2(u1.x, u1.y); a.u[3] = pk2(u1.z, u1.w);
      }
      Ax[rf] = a.s8;
    }
    short8 B1[4];
#pragma unroll
    for (int cf = 0; cf < 4; ++cf)
      B1[cf] = *(const short8*)&w1t[(c0 + cf * 16 + li) * 32 + g * 8];
#pragma unroll
    for (int rf = 0; rf < 2; ++rf)
#pragma unroll
      for (int cf = 0; cf < 4; ++cf)
        acc[rf][cf] = __builtin_amdgcn_mfma_f32_16x16x32_bf16(B1[cf], Ax[rf], acc[rf][cf], 0, 0, 0);
  }

  // epilogue layer 1 -> sH (relu; bias already in acc); 8B contiguous writes
#pragma unroll
  for (int rf = 0; rf < 2; ++rf) {
    int s = r0w + rf * 16 + li;
    unsigned short* dst = &sH[s * 128 + (g & 1) * 4];
    int sx = s & 7;
#pragma unroll
    for (int cf = 0; cf < 4; ++cf) {
      int gi = (c0 >> 3) + cf * 2 + (g >> 1);
      int slot = gi ^ sx;
      uint2 u;
      u.x = pk2(fmaxf(acc[rf][cf][0], 0.f), fmaxf(acc[rf][cf][1], 0.f));
      u.y = pk2(fmaxf(acc[rf][cf][2], 0.f), fmaxf(acc[rf][cf][3], 0.f));
      *(uint2*)(dst + slot * 8) = u;
    }
  }
  __syncthreads();

  // ---- layers 2 and 3 ----
  const unsigned short* wts[2] = { w2t, w3t };
  const float* bs[2] = { b2, b3 };
#pragma unroll 1
  for (int layer = 0; layer < 2; ++layer) {
    const unsigned short* wt = wts[layer];
    const float* bb = bs[layer];
#pragma unroll
    for (int ks = 0; ks < 4; ++ks)
#pragma unroll
      for (int cf = 0; cf < 4; ++cf)
        Bf[ks][cf] = *(const short8*)&wt[(c0 + cf * 16 + li) * 128 + ks * 32 + g * 8];

#pragma unroll
    for (int cf = 0; cf < 4; ++cf) {
      float4 b4 = *(const float4*)&bb[c0 + cf * 16 + g * 4];
#pragma unroll
      for (int rf = 0; rf < 2; ++rf) {
        acc[rf][cf][0] = b4.x; acc[rf][cf][1] = b4.y;
        acc[rf][cf][2] = b4.z; acc[rf][cf][3] = b4.w;
      }
    }

#pragma unroll
    for (int ks = 0; ks < 4; ++ks) {
      short8 Ar[2];
#pragma unroll
      for (int rf = 0; rf < 2; ++rf) {
        int s = r0w + rf * 16 + li;
        int slot = (ks * 4 + g) ^ (s & 7);
        Ar[rf] = *(const short8*)&sH[s * 128 + slot * 8];
      }
#pragma unroll
      for (int rf = 0; rf < 2; ++rf)
#pragma unroll
        for (int cf = 0; cf < 4; ++cf)
          acc[rf][cf] = __builtin_amdgcn_mfma_f32_16x16x32_bf16(Bf[ks][cf], Ar[rf], acc[rf][cf], 0, 0, 0);
    }
    __syncthreads();   // all sH reads done before overwrite

#pragma unroll
    for (int rf = 0; rf < 2; ++rf) {
      int s = r0w + rf * 16 + li;
      unsigned short* dst = &sH[s * 128 + (g & 1) * 4];
      int sx = s & 7;
#pragma unroll
      for (int cf = 0; cf < 4; ++cf) {
        int gi = (c0 >> 3) + cf * 2 + (g >> 1);
        int slot = gi ^ sx;
        uint2 u;
        u.x = pk2(fmaxf(acc[rf][cf][0], 0.f), fmaxf(acc[rf][cf][1], 0.f));
        u.y = pk2(fmaxf(acc[rf][cf][2], 0.f), fmaxf(acc[rf][cf][3], 0.f));
        *(uint2*)(dst + slot * 8) = u;
      }
    }
    __syncthreads();
  }

  // ---- coalesced copy-out: sH -> hout (16B/lane x 4) ----
  {
    int r = tid >> 2;             // 0..63
    int q = tid & 3;              // granule quarter
    int grow = rowBlk + r;
    if (grow < nrows) {
#pragma unroll
      for (int i = 0; i < 4; ++i) {
        int gi = q * 4 + i;       // logical granule (8 ch)
        int slot = gi ^ (r & 7);
        short8 v = *(const short8*)&sH[r * 128 + slot * 8];
        *(short8*)(hout + (size_t)grow * 128 + gi * 8) = v;
      }
    }
  }
}

// ---------------- CSR build ------------------------------------------------
__global__ __launch_bounds__(256)
void hist_kernel(const int* __restrict__ edst, int* __restrict__ cnt, int ne) {
  int i = blockIdx.x * blockDim.x + threadIdx.x;
  int stride = gridDim.x * blockDim.x;
  for (int e = i; e < ne; e += stride) atomicAdd(cnt + edst[e], 1);
}

// hierarchical scan: 1024 elems per block. s1: per-block sums.
__global__ __launch_bounds__(256)
void scan_sum_kernel(const int* __restrict__ cnt, int* __restrict__ bsum, int nph) {
  __shared__ int red[256];
  const int b = blockIdx.x, t = threadIdx.x;
  const int base = b * 1024 + t * 4;
  int s = 0;
#pragma unroll
  for (int i = 0; i < 4; ++i) {
    int idx = base + i;
    if (idx < nph) s += cnt[idx];
  }
  red[t] = s;
  __syncthreads();
  for (int d = 128; d > 0; d >>= 1) {
    if (t < d) red[t] += red[t + d];
    __syncthreads();
  }
  if (t == 0) bsum[b] = red[0];
}

// s2: exclusive scan of bsum[nb] (nb <= 256) -> boff; total -> *offs_end.
__global__ __launch_bounds__(256)
void scan_top_kernel(const int* __restrict__ bsum, int* __restrict__ boff,
                     int* __restrict__ offs_end, int nb) {
  __shared__ int part[256];
  const int t = threadIdx.x;
  part[t] = (t < nb) ? bsum[t] : 0;
  __syncthreads();
  for (int d = 1; d < 256; d <<= 1) {
    int v = (t >= d) ? part[t - d] : 0;
    __syncthreads();
    part[t] += v;
    __syncthreads();
  }
  if (t < nb) boff[t] = (t == 0) ? 0 : part[t - 1];
  if (t == 255) *offs_end = part[255];
}

// s3: per-block exclusive scan + base offset -> offs, cursor.
__global__ __launch_bounds__(256)
void scan_fill_kernel(const int* __restrict__ cnt, const int* __restrict__ boff,
                      int* __restrict__ offs, int* __restrict__ cursor, int nph) {
  __shared__ int part[256];
  const int b = blockIdx.x, t = threadIdx.x;
  const int base = b * 1024 + t * 4;
  int v[4];
  int s = 0;
#pragma unroll
  for (int i = 0; i < 4; ++i) {
    int idx = base + i;
    v[i] = (idx < nph) ? cnt[idx] : 0;
    s += v[i];
  }
  part[t] = s;
  __syncthreads();
  for (int d = 1; d < 256; d <<= 1) {
    int u = (t >= d) ? part[t - d] : 0;
    __syncthreads();
    part[t] += u;
    __syncthreads();
  }
  int run = boff[b] + ((t == 0) ? 0 : part[t - 1]);
#pragma unroll
  for (int i = 0; i < 4; ++i) {
    int idx = base + i;
    if (idx < nph) {
      offs[idx] = run;
      cursor[idx] = run;
      run += v[i];
    }
  }
}

__global__ __launch_bounds__(256)
void fill_kernel(const int* __restrict__ esrc, const int* __restrict__ edst,
                 int* __restrict__ cursor, int* __restrict__ csr, int ne) {
  int i = blockIdx.x * blockDim.x + threadIdx.x;
  int stride = gridDim.x * blockDim.x;
  for (int e = i; e < ne; e += stride) {
    int d = edst[e];
    int pos = atomicAdd(cursor + d, 1);
    csr[pos] = esrc[e];
  }
}

// ---------------- per-phase gather-reduce with 4-edge ILP -------------------
// 32-lane group per phase (lane owns 4 channels = ushort4); 4 edges in
// flight per iteration: 4 independent csr loads + 4 independent coalesced
// 256B gathers into 4 separate accumulators.
__global__ __launch_bounds__(256)
void agg_kernel(const unsigned short* __restrict__ h, const int* __restrict__ csr,
                const int* __restrict__ offs, unsigned short* __restrict__ agg,
                int nph) {
  const int grp = threadIdx.x >> 5;          // 0..7
  const int l   = threadIdx.x & 31;          // channel group: ch l*4..+3
  const int ph  = blockIdx.x * 8 + grp;
  if (ph >= nph) return;
  const int beg = offs[ph], end = offs[ph + 1];

  f32x4 a0 = (f32x4)0.f, a1 = (f32x4)0.f, a2 = (f32x4)0.f, a3 = (f32x4)0.f;
  int j = beg;
  for (; j + 4 <= end; j += 4) {
    int s0 = csr[j], s1 = csr[j + 1], s2 = csr[j + 2], s3 = csr[j + 3];
    ushort4 v0 = *(const ushort4*)(h + (size_t)s0 * 128 + l * 4);
    ushort4 v1 = *(const ushort4*)(h + (size_t)s1 * 128 + l * 4);
    ushort4 v2 = *(const ushort4*)(h + (size_t)s2 * 128 + l * 4);
    ushort4 v3 = *(const ushort4*)(h + (size_t)s3 * 128 + l * 4);
    a0[0] += bf2f(v0.x); a0[1] += bf2f(v0.y); a0[2] += bf2f(v0.z); a0[3] += bf2f(v0.w);
    a1[0] += bf2f(v1.x); a1[1] += bf2f(v1.y); a1[2] += bf2f(v1.z); a1[3] += bf2f(v1.w);
    a2[0] += bf2f(v2.x); a2[1] += bf2f(v2.y); a2[2] += bf2f(v2.z); a2[3] += bf2f(v2.w);
    a3[0] += bf2f(v3.x); a3[1] += bf2f(v3.y); a3[2] += bf2f(v3.z); a3[3] += bf2f(v3.w);
  }
  for (; j < end; ++j) {
    int s = csr[j];
    ushort4 v = *(const ushort4*)(h + (size_t)s * 128 + l * 4);
    a0[0] += bf2f(v.x); a0[1] += bf2f(v.y); a0[2] += bf2f(v.z); a0[3] += bf2f(v.w);
  }
  const float sc = 1.f / (float)max(end - beg, 1);
  ushort4 o;
  o.x = f2bf((a0[0] + a1[0] + a2[0] + a3[0]) * sc);
  o.y = f2bf((a0[1] + a1[1] + a2[1] + a3[1]) * sc);
  o.z = f2bf((a0[2] + a1[2] + a2[2] + a3[2]) * sc);
  o.w = f2bf((a0[3] + a1[3] + a2[3] + a3[3]) * sc);
  *(ushort4*)(agg + (size_t)ph * 128 + l * 4) = o;
}

// ---------------- phase MLP via MFMA (unchanged from round 7) ---------------
__global__ __launch_bounds__(256)
void phase_mlp_mfma(const unsigned short* __restrict__ aggb,
                    const unsigned short* __restrict__ w4t,
                    const unsigned short* __restrict__ w5t,
                    const float* __restrict__ b4, const float* __restrict__ b5,
                    const float* __restrict__ W6, const float* __restrict__ b6,
                    float* __restrict__ logits, int nph) {
  __shared__ unsigned short sH[64 * 128];
  float* sPart = (float*)sH;   // reused (after barrier) for head partials
  const int tid  = threadIdx.x;
  const int lane = tid & 63;
  const int w    = tid >> 6;
  const int rloc = lane & 15;
  const int g    = lane >> 4;
  const int r0w  = (w & 1) * 32;
  const int c0   = (w >> 1) * 64;
  const int rowBlk = blockIdx.x * 64;

  f32x4 acc[2][4];
  short8 Bf[4][4];

  // ---- layer 4: A from aggb global ----
#pragma unroll
  for (int ks = 0; ks < 4; ++ks)
#pragma unroll
    for (int cf = 0; cf < 4; ++cf)
      Bf[ks][cf] = *(const short8*)&w4t[(c0 + cf * 16 + rloc) * 128 + ks * 32 + g * 8];
#pragma unroll
  for (int rf = 0; rf < 2; ++rf)
#pragma unroll
    for (int cf = 0; cf < 4; ++cf) acc[rf][cf] = (f32x4)0.f;

  {
    const int row0 = rowBlk + r0w + rloc;
    const int row1 = row0 + 16;
#pragma unroll
    for (int ks = 0; ks < 4; ++ks) {
      short8 A0 = (short8)0, A1 = (short8)0;
      if (row0 < nph) A0 = *(const short8*)&aggb[(size_t)row0 * 128 + ks * 32 + g * 8];
      if (row1 < nph) A1 = *(const short8*)&aggb[(size_t)row1 * 128 + ks * 32 + g * 8];
#pragma unroll
      for (int cf = 0; cf < 4; ++cf) {
        acc[0][cf] = __builtin_amdgcn_mfma_f32_16x16x32_bf16(A0, Bf[ks][cf], acc[0][cf], 0, 0, 0);
        acc[1][cf] = __builtin_amdgcn_mfma_f32_16x16x32_bf16(A1, Bf[ks][cf], acc[1][cf], 0, 0, 0);
      }
    }
  }

  // epilogue layer 4 -> sH (swizzled)
  {
    float bv[4];
#pragma unroll
    for (int cf = 0; cf < 4; ++cf) bv[cf] = b4[c0 + cf * 16 + rloc];
#pragma unroll
    for (int rf = 0; rf < 2; ++rf)
#pragma unroll
      for (int cf = 0; cf < 4; ++cf)
#pragma unroll
        for (int i = 0; i < 4; ++i) {
          int row = r0w + rf * 16 + g * 4 + i;
          int col = c0 + cf * 16 + rloc;
          float v = fmaxf(acc[rf][cf][i] + bv[cf], 0.f);
          sH[row * 128 + (((col >> 3) ^ (row & 7)) << 3) + (col & 7)] = f2bf(v);
        }
  }
  __syncthreads();

  // ---- layer 5: A from sH ----
#pragma unroll
  for (int ks = 0; ks < 4; ++ks)
#pragma unroll
    for (int cf = 0; cf < 4; ++cf)
      Bf[ks][cf] = *(const short8*)&w5t[(c0 + cf * 16 + rloc) * 128 + ks * 32 + g * 8];
#pragma unroll
  for (int rf = 0; rf < 2; ++rf)
#pragma unroll
    for (int cf = 0; cf < 4; ++cf) acc[rf][cf] = (f32x4)0.f;

#pragma unroll
  for (int ks = 0; ks < 4; ++ks) {
    short8 A0, A1;
    {
      int row = r0w + rloc;
      int slot = (ks * 4 + g) ^ (row & 7);
      A0 = *(const short8*)&sH[row * 128 + slot * 8];
    }
    {
      int row = r0w + 16 + rloc;
      int slot = (ks * 4 + g) ^ (row & 7);
      A1 = *(const short8*)&sH[row * 128 + slot * 8];
    }
#pragma unroll
    for (int cf = 0; cf < 4; ++cf) {
      acc[0][cf] = __builtin_amdgcn_mfma_f32_16x16x32_bf16(A0, Bf[ks][cf], acc[0][cf], 0, 0, 0);
      acc[1][cf] = __builtin_amdgcn_mfma_f32_16x16x32_bf16(A1, Bf[ks][cf], acc[1][cf], 0, 0, 0);
    }
  }

  // ---- head: logits[r] = relu(acc + b5) . W6 + b6 ----
  float part8[2][4];
  {
    float bv[4], wv[4];
#pragma unroll
    for (int cf = 0; cf < 4; ++cf) {
      bv[cf] = b5[c0 + cf * 16 + rloc];
      wv[cf] = W6[c0 + cf * 16 + rloc];
    }
#pragma unroll
    for (int rf = 0; rf < 2; ++rf)
#pragma unroll
      for (int i = 0; i < 4; ++i) {
        float p = 0.f;
#pragma unroll
        for (int cf = 0; cf < 4; ++cf)
          p += fmaxf(acc[rf][cf][i] + bv[cf], 0.f) * wv[cf];
        part8[rf][i] = p;
      }
  }
#pragma unroll
  for (int m = 1; m < 16; m <<= 1) {
#pragma unroll
    for (int rf = 0; rf < 2; ++rf)
#pragma unroll
      for (int i = 0; i < 4; ++i)
        part8[rf][i] += __shfl_xor(part8[rf][i], m, 64);
  }
  __syncthreads();
  if (rloc == 0) {
#pragma unroll
    for (int rf = 0; rf < 2; ++rf)
#pragma unroll
      for (int i = 0; i < 4; ++i)
        sPart[(w >> 1) * 64 + r0w + rf * 16 + g * 4 + i] = part8[rf][i];
  }
  __syncthreads();
  if (tid < 64) {
    int gr = rowBlk + tid;
    if (gr < nph) logits[gr] = sPart[tid] + sPart[64 + tid] + b6[0];
  }
}

// ---------------------------------------------------------------------------
extern "C" void kernel_launch(void* const* d_in, const int* in_sizes, int n_in,
                              void* d_out, int out_size, void* d_ws, size_t ws_size,
                              hipStream_t stream) {
  const float* x  = (const float*)d_in[0];
  const float* W1 = (const float*)d_in[1];
  const float* b1 = (const float*)d_in[2];
  const float* W2 = (const float*)d_in[3];
  const float* b2 = (const float*)d_in[4];
  const float* W3 = (const float*)d_in[5];
  const float* b3 = (const float*)d_in[6];
  const float* W4 = (const float*)d_in[7];
  const float* b4 = (const float*)d_in[8];
  const float* W5 = (const float*)d_in[9];
  const float* b5 = (const float*)d_in[10];
  const float* W6 = (const float*)d_in[11];
  const float* b6 = (const float*)d_in[12];
  const int* esrc = (const int*)d_in[13];
  const int* edst = (const int*)d_in[14];

  const int nmov = in_sizes[0] / 16;
  const int ne   = in_sizes[13];
  const int nph  = out_size;

  char* ws = (char*)d_ws;
  size_t off = 0;
  auto take = [&](size_t bytes) {
    char* p = ws + off;
    off = (off + bytes + 255) & ~(size_t)255;
    return p;
  };
  unsigned short* hbuf = (unsigned short*)take((size_t)nmov * 128 * 2); // 128 MB
  int* csr             = (int*)take((size_t)ne * 4);                   //   4 MB
  int* cnt             = (int*)take((size_t)nph * 4);
  int* offs            = (int*)take(((size_t)nph + 1) * 4);
  int* cursor          = (int*)take((size_t)nph * 4);
  unsigned short* aggb = (unsigned short*)take((size_t)nph * 128 * 2); //  32 MB
  unsigned short* w1t  = (unsigned short*)take(128 * 32 * 2);
  unsigned short* w2t  = (unsigned short*)take(128 * 128 * 2);
  unsigned short* w3t  = (unsigned short*)take(128 * 128 * 2);
  unsigned short* w4t  = (unsigned short*)take(128 * 128 * 2);
  unsigned short* w5t  = (unsigned short*)take(128 * 128 * 2);
  const int nb = (nph + 1023) / 1024;            // <= 256 for nph <= 262144
  int* bsum            = (int*)take((size_t)nb * 4);
  int* boff            = (int*)take((size_t)nb * 4);
  if (off > ws_size) return;

  (void)hipMemsetAsync(cnt, 0, (size_t)nph * 4, stream);

  prep_weights<<<64, 256, 0, stream>>>(W1, W2, W3, W4, W5, w1t, w2t, w3t, w4t, w5t);

  int movBlocks = (nmov + 63) / 64;
  mov_mlp_mfma<<<movBlocks, 256, 0, stream>>>(x, w1t, w2t, w3t, b1, b2, b3, hbuf, nmov);

  hist_kernel<<<1024, 256, 0, stream>>>(edst, cnt, ne);
  scan_sum_kernel<<<nb, 256, 0, stream>>>(cnt, bsum, nph);
  scan_top_kernel<<<1, 256, 0, stream>>>(bsum, boff, offs + nph, nb);
  scan_fill_kernel<<<nb, 256, 0, stream>>>(cnt, boff, offs, cursor, nph);
  fill_kernel<<<1024, 256, 0, stream>>>(esrc, edst, cursor, csr, ne);

  int aggBlocks = (nph + 7) / 8;
  agg_kernel<<<aggBlocks, 256, 0, stream>>>(hbuf, csr, offs, aggb, nph);

  int phBlocks = (nph + 63) / 64;
  phase_mlp_mfma<<<phBlocks, 256, 0, stream>>>(aggb, w4t, w5t, b4, b5, W6, b6,
                                               (float*)d_out, nph);
}

// Round 11
// 378.283 us; speedup vs baseline: 1.2144x; 1.0037x over previous
//
#include <hip/hip_runtime.h>
#include <hip/hip_bf16.h>

// ---------------------------------------------------------------------------
// GraphActorNetwork: movement MLP (16->128->128->128) -> scatter-mean over
// edges -> phase MLP (128->128->128->1).
// Round 11: mov_mlp_mfma latency-bound (r10: 168us; all pipes sum to ~50us
// if overlapped -> barrier-phase stall, m233 signature). Fix: (1) block=128
// (2 waves, 32-row tile, 8KB LDS) -> barriers couple only a wave pair and
// occupancy ceiling doubles (more independent blocks/CU); (2) epilogue bf16
// packing via __float22bfloat162_rn (compiler cvt) instead of 5-op manual
// RNE (~600 VALU/wave saved). Layout/swizzle/operand-swap unchanged.
// agg (4-edge ILP), CSR build, phase MLP unchanged from round 10 (380us).
// ---------------------------------------------------------------------------

typedef __attribute__((ext_vector_type(8))) short short8;
typedef __attribute__((ext_vector_type(4))) float f32x4;

union U8 { short8 s8; unsigned int u[4]; };

__device__ __forceinline__ float bf2f(unsigned short u) {
  return __uint_as_float(((unsigned int)u) << 16);
}
__device__ __forceinline__ unsigned short f2bf(float f) {
  unsigned int u = __float_as_uint(f);
  u = (u + 0x7fffu + ((u >> 16) & 1u)) >> 16;   // RNE
  return (unsigned short)u;
}
// compiler-generated packed f32x2 -> bf16x2 (RNE), bit-moved without bit_cast
__device__ __forceinline__ unsigned int pk2(float a, float b) {
  __hip_bfloat162 h = __float22bfloat162_rn(make_float2(a, b));
  unsigned int u;
  __builtin_memcpy(&u, &h, 4);
  return u;
}

// ---------------- weight prep: f32 -> bf16 transposed -----------------------
// w1t: [128 c][32 k] (k 16..31 zero);  w2t..w5t: [128 c][128 k]
__global__ __launch_bounds__(256)
void prep_weights(const float* __restrict__ W1, const float* __restrict__ W2,
                  const float* __restrict__ W3, const float* __restrict__ W4,
                  const float* __restrict__ W5,
                  unsigned short* __restrict__ w1t, unsigned short* __restrict__ w2t,
                  unsigned short* __restrict__ w3t, unsigned short* __restrict__ w4t,
                  unsigned short* __restrict__ w5t) {
  int t = blockIdx.x * blockDim.x + threadIdx.x;
  int stride = gridDim.x * blockDim.x;
  if (t < 128 * 32) {
    int c = t >> 5, k = t & 31;
    w1t[t] = (k < 16) ? f2bf(W1[k * 128 + c]) : 0;
  }
  for (int i = t; i < 128 * 128; i += stride) {
    int c = i >> 7, k = i & 127;
    w2t[i] = f2bf(W2[k * 128 + c]);
    w3t[i] = f2bf(W3[k * 128 + c]);
    w4t[i] = f2bf(W4[k * 128 + c]);
    w5t[i] = f2bf(W5[k * 128 + c]);
  }
}

// ---------------- movement MLP via MFMA, swapped operands, 2-wave blocks ----
// Block: 128 threads = 2 waves, tile 32 rows x 128 cols.
// Wave w: rows 0..31 (2 rf), cols w*64..+63 (4 cf).
// D^T = mfma(Wfrag, actfrag): lane holds sample li (per rf), channels
// cf*16 + g*4..+3. sH bf16 [32 samples][128 ch], 16B granules (8 ch)
// XOR-swizzled: slot = granule ^ (sample&7).
__global__ __launch_bounds__(128)
void mov_mlp_mfma(const float* __restrict__ x,
                  const unsigned short* __restrict__ w1t,
                  const unsigned short* __restrict__ w2t,
                  const unsigned short* __restrict__ w3t,
                  const float* __restrict__ b1, const float* __restrict__ b2,
                  const float* __restrict__ b3,
                  unsigned short* __restrict__ hout, int nrows) {
  __shared__ unsigned short sH[32 * 128];   // 8 KB
  const int tid  = threadIdx.x;
  const int lane = tid & 63;
  const int w    = tid >> 6;      // 0..1
  const int li   = lane & 15;     // sample-in-frag
  const int g    = lane >> 4;     // k-group; D^T ch sub-block g*4..+3
  const int c0   = w * 64;        // wave col base
  const int rowBlk = blockIdx.x * 32;

  f32x4 acc[2][4];   // [rf][cf]
  short8 Bf[4][4];   // [ks][cf] weight frags

  // ---- layer 1: act from global x (K=32, k 16..31 zero) ----
#pragma unroll
  for (int cf = 0; cf < 4; ++cf) {
    float4 b4 = *(const float4*)&b1[c0 + cf * 16 + g * 4];
#pragma unroll
    for (int rf = 0; rf < 2; ++rf) {
      acc[rf][cf][0] = b4.x; acc[rf][cf][1] = b4.y;
      acc[rf][cf][2] = b4.z; acc[rf][cf][3] = b4.w;
    }
  }
  {
    short8 Ax[2];
#pragma unroll
    for (int rf = 0; rf < 2; ++rf) {
      U8 a; a.s8 = (short8)0;
      int row = rowBlk + rf * 16 + li;
      if (g < 2 && row < nrows) {
        const float* xp = x + (size_t)row * 16 + g * 8;
        float4 u0 = *(const float4*)xp;
        float4 u1 = *(const float4*)(xp + 4);
        a.u[0] = pk2(u0.x, u0.y); a.u[1] = pk2(u0.z, u0.w);
        a.u[2] = pk2(u1.x, u1.y); a.u[3] = pk2(u1.z, u1.w);
      }
      Ax[rf] = a.s8;
    }
    short8 B1[4];
#pragma unroll
    for (int cf = 0; cf < 4; ++cf)
      B1[cf] = *(const short8*)&w1t[(c0 + cf * 16 + li) * 32 + g * 8];
#pragma unroll
    for (int rf = 0; rf < 2; ++rf)
#pragma unroll
      for (int cf = 0; cf < 4; ++cf)
        acc[rf][cf] = __builtin_amdgcn_mfma_f32_16x16x32_bf16(B1[cf], Ax[rf], acc[rf][cf], 0, 0, 0);
  }

  // epilogue layer 1 -> sH (relu; bias already in acc); 8B contiguous writes
#pragma unroll
  for (int rf = 0; rf < 2; ++rf) {
    int s = rf * 16 + li;
    unsigned short* dst = &sH[s * 128 + (g & 1) * 4];
    int sx = s & 7;
#pragma unroll
    for (int cf = 0; cf < 4; ++cf) {
      int gi = (c0 >> 3) + cf * 2 + (g >> 1);
      int slot = gi ^ sx;
      uint2 u;
      u.x = pk2(fmaxf(acc[rf][cf][0], 0.f), fmaxf(acc[rf][cf][1], 0.f));
      u.y = pk2(fmaxf(acc[rf][cf][2], 0.f), fmaxf(acc[rf][cf][3], 0.f));
      *(uint2*)(dst + slot * 8) = u;
    }
  }
  __syncthreads();

  // ---- layers 2 and 3 ----
  const unsigned short* wts[2] = { w2t, w3t };
  const float* bs[2] = { b2, b3 };
#pragma unroll 1
  for (int layer = 0; layer < 2; ++layer) {
    const unsigned short* wt = wts[layer];
    const float* bb = bs[layer];
#pragma unroll
    for (int ks = 0; ks < 4; ++ks)
#pragma unroll
      for (int cf = 0; cf < 4; ++cf)
        Bf[ks][cf] = *(const short8*)&wt[(c0 + cf * 16 + li) * 128 + ks * 32 + g * 8];

#pragma unroll
    for (int cf = 0; cf < 4; ++cf) {
      float4 b4 = *(const float4*)&bb[c0 + cf * 16 + g * 4];
#pragma unroll
      for (int rf = 0; rf < 2; ++rf) {
        acc[rf][cf][0] = b4.x; acc[rf][cf][1] = b4.y;
        acc[rf][cf][2] = b4.z; acc[rf][cf][3] = b4.w;
      }
    }

#pragma unroll
    for (int ks = 0; ks < 4; ++ks) {
      short8 Ar[2];
#pragma unroll
      for (int rf = 0; rf < 2; ++rf) {
        int s = rf * 16 + li;
        int slot = (ks * 4 + g) ^ (s & 7);
        Ar[rf] = *(const short8*)&sH[s * 128 + slot * 8];
      }
#pragma unroll
      for (int rf = 0; rf < 2; ++rf)
#pragma unroll
        for (int cf = 0; cf < 4; ++cf)
          acc[rf][cf] = __builtin_amdgcn_mfma_f32_16x16x32_bf16(Bf[ks][cf], Ar[rf], acc[rf][cf], 0, 0, 0);
    }
    __syncthreads();   // all sH reads done before overwrite

#pragma unroll
    for (int rf = 0; rf < 2; ++rf) {
      int s = rf * 16 + li;
      unsigned short* dst = &sH[s * 128 + (g & 1) * 4];
      int sx = s & 7;
#pragma unroll
      for (int cf = 0; cf < 4; ++cf) {
        int gi = (c0 >> 3) + cf * 2 + (g >> 1);
        int slot = gi ^ sx;
        uint2 u;
        u.x = pk2(fmaxf(acc[rf][cf][0], 0.f), fmaxf(acc[rf][cf][1], 0.f));
        u.y = pk2(fmaxf(acc[rf][cf][2], 0.f), fmaxf(acc[rf][cf][3], 0.f));
        *(uint2*)(dst + slot * 8) = u;
      }
    }
    __syncthreads();
  }

  // ---- coalesced copy-out: sH -> hout (16B/lane x 4) ----
  {
    int r = tid >> 2;             // 0..31
    int q = tid & 3;              // granule quarter
    int grow = rowBlk + r;
    if (grow < nrows) {
#pragma unroll
      for (int i = 0; i < 4; ++i) {
        int gi = q * 4 + i;       // logical granule (8 ch)
        int slot = gi ^ (r & 7);
        short8 v = *(const short8*)&sH[r * 128 + slot * 8];
        *(short8*)(hout + (size_t)grow * 128 + gi * 8) = v;
      }
    }
  }
}

// ---------------- CSR build ------------------------------------------------
__global__ __launch_bounds__(256)
void hist_kernel(const int* __restrict__ edst, int* __restrict__ cnt, int ne) {
  int i = blockIdx.x * blockDim.x + threadIdx.x;
  int stride = gridDim.x * blockDim.x;
  for (int e = i; e < ne; e += stride) atomicAdd(cnt + edst[e], 1);
}

// hierarchical scan: 1024 elems per block. s1: per-block sums.
__global__ __launch_bounds__(256)
void scan_sum_kernel(const int* __restrict__ cnt, int* __restrict__ bsum, int nph) {
  __shared__ int red[256];
  const int b = blockIdx.x, t = threadIdx.x;
  const int base = b * 1024 + t * 4;
  int s = 0;
#pragma unroll
  for (int i = 0; i < 4; ++i) {
    int idx = base + i;
    if (idx < nph) s += cnt[idx];
  }
  red[t] = s;
  __syncthreads();
  for (int d = 128; d > 0; d >>= 1) {
    if (t < d) red[t] += red[t + d];
    __syncthreads();
  }
  if (t == 0) bsum[b] = red[0];
}

// s2: exclusive scan of bsum[nb] (nb <= 256) -> boff; total -> *offs_end.
__global__ __launch_bounds__(256)
void scan_top_kernel(const int* __restrict__ bsum, int* __restrict__ boff,
                     int* __restrict__ offs_end, int nb) {
  __shared__ int part[256];
  const int t = threadIdx.x;
  part[t] = (t < nb) ? bsum[t] : 0;
  __syncthreads();
  for (int d = 1; d < 256; d <<= 1) {
    int v = (t >= d) ? part[t - d] : 0;
    __syncthreads();
    part[t] += v;
    __syncthreads();
  }
  if (t < nb) boff[t] = (t == 0) ? 0 : part[t - 1];
  if (t == 255) *offs_end = part[255];
}

// s3: per-block exclusive scan + base offset -> offs, cursor.
__global__ __launch_bounds__(256)
void scan_fill_kernel(const int* __restrict__ cnt, const int* __restrict__ boff,
                      int* __restrict__ offs, int* __restrict__ cursor, int nph) {
  __shared__ int part[256];
  const int b = blockIdx.x, t = threadIdx.x;
  const int base = b * 1024 + t * 4;
  int v[4];
  int s = 0;
#pragma unroll
  for (int i = 0; i < 4; ++i) {
    int idx = base + i;
    v[i] = (idx < nph) ? cnt[idx] : 0;
    s += v[i];
  }
  part[t] = s;
  __syncthreads();
  for (int d = 1; d < 256; d <<= 1) {
    int u = (t >= d) ? part[t - d] : 0;
    __syncthreads();
    part[t] += u;
    __syncthreads();
  }
  int run = boff[b] + ((t == 0) ? 0 : part[t - 1]);
#pragma unroll
  for (int i = 0; i < 4; ++i) {
    int idx = base + i;
    if (idx < nph) {
      offs[idx] = run;
      cursor[idx] = run;
      run += v[i];
    }
  }
}

__global__ __launch_bounds__(256)
void fill_kernel(const int* __restrict__ esrc, const int* __restrict__ edst,
                 int* __restrict__ cursor, int* __restrict__ csr, int ne) {
  int i = blockIdx.x * blockDim.x + threadIdx.x;
  int stride = gridDim.x * blockDim.x;
  for (int e = i; e < ne; e += stride) {
    int d = edst[e];
    int pos = atomicAdd(cursor + d, 1);
    csr[pos] = esrc[e];
  }
}

// ---------------- per-phase gather-reduce with 4-edge ILP -------------------
__global__ __launch_bounds__(256)
void agg_kernel(const unsigned short* __restrict__ h, const int* __restrict__ csr,
                const int* __restrict__ offs, unsigned short* __restrict__ agg,
                int nph) {
  const int grp = threadIdx.x >> 5;          // 0..7
  const int l   = threadIdx.x & 31;          // channel group: ch l*4..+3
  const int ph  = blockIdx.x * 8 + grp;
  if (ph >= nph) return;
  const int beg = offs[ph], end = offs[ph + 1];

  f32x4 a0 = (f32x4)0.f, a1 = (f32x4)0.f, a2 = (f32x4)0.f, a3 = (f32x4)0.f;
  int j = beg;
  for (; j + 4 <= end; j += 4) {
    int s0 = csr[j], s1 = csr[j + 1], s2 = csr[j + 2], s3 = csr[j + 3];
    ushort4 v0 = *(const ushort4*)(h + (size_t)s0 * 128 + l * 4);
    ushort4 v1 = *(const ushort4*)(h + (size_t)s1 * 128 + l * 4);
    ushort4 v2 = *(const ushort4*)(h + (size_t)s2 * 128 + l * 4);
    ushort4 v3 = *(const ushort4*)(h + (size_t)s3 * 128 + l * 4);
    a0[0] += bf2f(v0.x); a0[1] += bf2f(v0.y); a0[2] += bf2f(v0.z); a0[3] += bf2f(v0.w);
    a1[0] += bf2f(v1.x); a1[1] += bf2f(v1.y); a1[2] += bf2f(v1.z); a1[3] += bf2f(v1.w);
    a2[0] += bf2f(v2.x); a2[1] += bf2f(v2.y); a2[2] += bf2f(v2.z); a2[3] += bf2f(v2.w);
    a3[0] += bf2f(v3.x); a3[1] += bf2f(v3.y); a3[2] += bf2f(v3.z); a3[3] += bf2f(v3.w);
  }
  for (; j < end; ++j) {
    int s = csr[j];
    ushort4 v = *(const ushort4*)(h + (size_t)s * 128 + l * 4);
    a0[0] += bf2f(v.x); a0[1] += bf2f(v.y); a0[2] += bf2f(v.z); a0[3] += bf2f(v.w);
  }
  const float sc = 1.f / (float)max(end - beg, 1);
  ushort4 o;
  o.x = f2bf((a0[0] + a1[0] + a2[0] + a3[0]) * sc);
  o.y = f2bf((a0[1] + a1[1] + a2[1] + a3[1]) * sc);
  o.z = f2bf((a0[2] + a1[2] + a2[2] + a3[2]) * sc);
  o.w = f2bf((a0[3] + a1[3] + a2[3] + a3[3]) * sc);
  *(ushort4*)(agg + (size_t)ph * 128 + l * 4) = o;
}

// ---------------- phase MLP via MFMA (unchanged) ----------------------------
__global__ __launch_bounds__(256)
void phase_mlp_mfma(const unsigned short* __restrict__ aggb,
                    const unsigned short* __restrict__ w4t,
                    const unsigned short* __restrict__ w5t,
                    const float* __restrict__ b4, const float* __restrict__ b5,
                    const float* __restrict__ W6, const float* __restrict__ b6,
                    float* __restrict__ logits, int nph) {
  __shared__ unsigned short sH[64 * 128];
  float* sPart = (float*)sH;   // reused (after barrier) for head partials
  const int tid  = threadIdx.x;
  const int lane = tid & 63;
  const int w    = tid >> 6;
  const int rloc = lane & 15;
  const int g    = lane >> 4;
  const int r0w  = (w & 1) * 32;
  const int c0   = (w >> 1) * 64;
  const int rowBlk = blockIdx.x * 64;

  f32x4 acc[2][4];
  short8 Bf[4][4];

  // ---- layer 4: A from aggb global ----
#pragma unroll
  for (int ks = 0; ks < 4; ++ks)
#pragma unroll
    for (int cf = 0; cf < 4; ++cf)
      Bf[ks][cf] = *(const short8*)&w4t[(c0 + cf * 16 + rloc) * 128 + ks * 32 + g * 8];
#pragma unroll
  for (int rf = 0; rf < 2; ++rf)
#pragma unroll
    for (int cf = 0; cf < 4; ++cf) acc[rf][cf] = (f32x4)0.f;

  {
    const int row0 = rowBlk + r0w + rloc;
    const int row1 = row0 + 16;
#pragma unroll
    for (int ks = 0; ks < 4; ++ks) {
      short8 A0 = (short8)0, A1 = (short8)0;
      if (row0 < nph) A0 = *(const short8*)&aggb[(size_t)row0 * 128 + ks * 32 + g * 8];
      if (row1 < nph) A1 = *(const short8*)&aggb[(size_t)row1 * 128 + ks * 32 + g * 8];
#pragma unroll
      for (int cf = 0; cf < 4; ++cf) {
        acc[0][cf] = __builtin_amdgcn_mfma_f32_16x16x32_bf16(A0, Bf[ks][cf], acc[0][cf], 0, 0, 0);
        acc[1][cf] = __builtin_amdgcn_mfma_f32_16x16x32_bf16(A1, Bf[ks][cf], acc[1][cf], 0, 0, 0);
      }
    }
  }

  // epilogue layer 4 -> sH (swizzled)
  {
    float bv[4];
#pragma unroll
    for (int cf = 0; cf < 4; ++cf) bv[cf] = b4[c0 + cf * 16 + rloc];
#pragma unroll
    for (int rf = 0; rf < 2; ++rf)
#pragma unroll
      for (int cf = 0; cf < 4; ++cf)
#pragma unroll
        for (int i = 0; i < 4; ++i) {
          int row = r0w + rf * 16 + g * 4 + i;
          int col = c0 + cf * 16 + rloc;
          float v = fmaxf(acc[rf][cf][i] + bv[cf], 0.f);
          sH[row * 128 + (((col >> 3) ^ (row & 7)) << 3) + (col & 7)] = f2bf(v);
        }
  }
  __syncthreads();

  // ---- layer 5: A from sH ----
#pragma unroll
  for (int ks = 0; ks < 4; ++ks)
#pragma unroll
    for (int cf = 0; cf < 4; ++cf)
      Bf[ks][cf] = *(const short8*)&w5t[(c0 + cf * 16 + rloc) * 128 + ks * 32 + g * 8];
#pragma unroll
  for (int rf = 0; rf < 2; ++rf)
#pragma unroll
    for (int cf = 0; cf < 4; ++cf) acc[rf][cf] = (f32x4)0.f;

#pragma unroll
  for (int ks = 0; ks < 4; ++ks) {
    short8 A0, A1;
    {
      int row = r0w + rloc;
      int slot = (ks * 4 + g) ^ (row & 7);
      A0 = *(const short8*)&sH[row * 128 + slot * 8];
    }
    {
      int row = r0w + 16 + rloc;
      int slot = (ks * 4 + g) ^ (row & 7);
      A1 = *(const short8*)&sH[row * 128 + slot * 8];
    }
#pragma unroll
    for (int cf = 0; cf < 4; ++cf) {
      acc[0][cf] = __builtin_amdgcn_mfma_f32_16x16x32_bf16(A0, Bf[ks][cf], acc[0][cf], 0, 0, 0);
      acc[1][cf] = __builtin_amdgcn_mfma_f32_16x16x32_bf16(A1, Bf[ks][cf], acc[1][cf], 0, 0, 0);
    }
  }

  // ---- head: logits[r] = relu(acc + b5) . W6 + b6 ----
  float part8[2][4];
  {
    float bv[4], wv[4];
#pragma unroll
    for (int cf = 0; cf < 4; ++cf) {
      bv[cf] = b5[c0 + cf * 16 + rloc];
      wv[cf] = W6[c0 + cf * 16 + rloc];
    }
#pragma unroll
    for (int rf = 0; rf < 2; ++rf)
#pragma unroll
      for (int i = 0; i < 4; ++i) {
        float p = 0.f;
#pragma unroll
        for (int cf = 0; cf < 4; ++cf)
          p += fmaxf(acc[rf][cf][i] + bv[cf], 0.f) * wv[cf];
        part8[rf][i] = p;
      }
  }
#pragma unroll
  for (int m = 1; m < 16; m <<= 1) {
#pragma unroll
    for (int rf = 0; rf < 2; ++rf)
#pragma unroll
      for (int i = 0; i < 4; ++i)
        part8[rf][i] += __shfl_xor(part8[rf][i], m, 64);
  }
  __syncthreads();
  if (rloc == 0) {
#pragma unroll
    for (int rf = 0; rf < 2; ++rf)
#pragma unroll
      for (int i = 0; i < 4; ++i)
        sPart[(w >> 1) * 64 + r0w + rf * 16 + g * 4 + i] = part8[rf][i];
  }
  __syncthreads();
  if (tid < 64) {
    int gr = rowBlk + tid;
    if (gr < nph) logits[gr] = sPart[tid] + sPart[64 + tid] + b6[0];
  }
}

// ---------------------------------------------------------------------------
extern "C" void kernel_launch(void* const* d_in, const int* in_sizes, int n_in,
                              void* d_out, int out_size, void* d_ws, size_t ws_size,
                              hipStream_t stream) {
  const float* x  = (const float*)d_in[0];
  const float* W1 = (const float*)d_in[1];
  const float* b1 = (const float*)d_in[2];
  const float* W2 = (const float*)d_in[3];
  const float* b2 = (const float*)d_in[4];
  const float* W3 = (const float*)d_in[5];
  const float* b3 = (const float*)d_in[6];
  const float* W4 = (const float*)d_in[7];
  const float* b4 = (const float*)d_in[8];
  const float* W5 = (const float*)d_in[9];
  const float* b5 = (const float*)d_in[10];
  const float* W6 = (const float*)d_in[11];
  const float* b6 = (const float*)d_in[12];
  const int* esrc = (const int*)d_in[13];
  const int* edst = (const int*)d_in[14];

  const int nmov = in_sizes[0] / 16;
  const int ne   = in_sizes[13];
  const int nph  = out_size;

  char* ws = (char*)d_ws;
  size_t off = 0;
  auto take = [&](size_t bytes) {
    char* p = ws + off;
    off = (off + bytes + 255) & ~(size_t)255;
    return p;
  };
  unsigned short* hbuf = (unsigned short*)take((size_t)nmov * 128 * 2); // 128 MB
  int* csr             = (int*)take((size_t)ne * 4);                   //   4 MB
  int* cnt             = (int*)take((size_t)nph * 4);
  int* offs            = (int*)take(((size_t)nph + 1) * 4);
  int* cursor          = (int*)take((size_t)nph * 4);
  unsigned short* aggb = (unsigned short*)take((size_t)nph * 128 * 2); //  32 MB
  unsigned short* w1t  = (unsigned short*)take(128 * 32 * 2);
  unsigned short* w2t  = (unsigned short*)take(128 * 128 * 2);
  unsigned short* w3t  = (unsigned short*)take(128 * 128 * 2);
  unsigned short* w4t  = (unsigned short*)take(128 * 128 * 2);
  unsigned short* w5t  = (unsigned short*)take(128 * 128 * 2);
  const int nb = (nph + 1023) / 1024;            // <= 256 for nph <= 262144
  int* bsum            = (int*)take((size_t)nb * 4);
  int* boff            = (int*)take((size_t)nb * 4);
  if (off > ws_size) return;

  (void)hipMemsetAsync(cnt, 0, (size_t)nph * 4, stream);

  prep_weights<<<64, 256, 0, stream>>>(W1, W2, W3, W4, W5, w1t, w2t, w3t, w4t, w5t);

  int movBlocks = (nmov + 31) / 32;
  mov_mlp_mfma<<<movBlocks, 128, 0, stream>>>(x, w1t, w2t, w3t, b1, b2, b3, hbuf, nmov);

  hist_kernel<<<1024, 256, 0, stream>>>(edst, cnt, ne);
  scan_sum_kernel<<<nb, 256, 0, stream>>>(cnt, bsum, nph);
  scan_top_kernel<<<1, 256, 0, stream>>>(bsum, boff, offs + nph, nb);
  scan_fill_kernel<<<nb, 256, 0, stream>>>(cnt, boff, offs, cursor, nph);
  fill_kernel<<<1024, 256, 0, stream>>>(esrc, edst, cursor, csr, ne);

  int aggBlocks = (nph + 7) / 8;
  agg_kernel<<<aggBlocks, 256, 0, stream>>>(hbuf, csr, offs, aggb, nph);

  int phBlocks = (nph + 63) / 64;
  phase_mlp_mfma<<<phBlocks, 256, 0, stream>>>(aggb, w4t, w5t, b4, b5, W6, b6,
                                               (float*)d_out, nph);
}